// Round 16
// baseline (4155.880 us; speedup 1.0000x reference)
//
#include <hip/hip_runtime.h>
#include <hip/hip_bf16.h>
#include <stdint.h>

#define B_   64
#define T_   1024
#define I_   512
#define H_   1024
#define TOP_ 256
#define NWG  256
#define NTHR 512

typedef __bf16 bf16x8 __attribute__((ext_vector_type(8)));
typedef float  f32x4  __attribute__((ext_vector_type(4)));
typedef uint32_t u32x4 __attribute__((ext_vector_type(4)));

struct P {
  const float *x, *h0, *c0, *topic, *Wi, *bi, *Wh, *bh, *Wt, *bt;
  float *out, *hN, *cN;
  uint16_t *hs;       // h slots [2][8 grp][8 b][1024] bf16 — sc01/IF$ ops ONLY
  uint32_t *flags;    // [8 grp][32 cg], 64B apart — agent st / sc01 ld ONLY
  uint32_t *bar;      // prologue barrier counter (zeroed by lstm_init each launch)
};

__device__ __forceinline__ bf16x8 cvt8(float4 f0, float4 f1) {
  bf16x8 v;
  v[0]=(__bf16)f0.x; v[1]=(__bf16)f0.y; v[2]=(__bf16)f0.z; v[3]=(__bf16)f0.w;
  v[4]=(__bf16)f1.x; v[5]=(__bf16)f1.y; v[6]=(__bf16)f1.z; v[7]=(__bf16)f1.w;
  return v;
}
__device__ __forceinline__ float sigm(float x) { return 1.f / (1.f + __expf(-x)); }
__device__ __forceinline__ float tanh_fast(float z) {
  z = fminf(fmaxf(z, -15.f), 15.f);
  float e = __expf(2.f * z);
  return (e - 1.f) / (e + 1.f);
}
// IF$ coherence point (cross-XCD coherent) — the ONLY class used on hs/flags/bar
__device__ __forceinline__ u32x4 ld16_sc01(const void* a) {
  u32x4 r; asm volatile("global_load_dwordx4 %0, %1, off sc0 sc1" : "=v"(r) : "v"(a) : "memory"); return r;
}
__device__ __forceinline__ uint32_t ld32_sc01(const void* a) {
  uint32_t r; asm volatile("global_load_dword %0, %1, off sc0 sc1" : "=v"(r) : "v"(a) : "memory"); return r;
}
__device__ __forceinline__ void st16_sc01(void* a, u32x4 v) {
  asm volatile("global_store_dwordx4 %0, %1, off sc0 sc1" :: "v"(a), "v"(v) : "memory");
}
#define WAITV0() asm volatile("s_waitcnt vmcnt(0)" ::: "memory")

__global__ void lstm_init(P p) {
  if (threadIdx.x == 0)
    __hip_atomic_store(p.bar, 0u, __ATOMIC_RELAXED, __HIP_MEMORY_SCOPE_AGENT);
}

__global__ __launch_bounds__(NTHR, 2) void lstm_persist(P p) {
  __shared__ ushort wlds[8][8][64][8];              // 64 KB: weight chunk i==5
  __shared__ float  pl[8][132][8];                  // 33.8 KB: [wave][gate row][batch]
  __shared__ __align__(16) ushort hlds[8][32];      // 512 B: h gather for 16B publish

  const int tid  = threadIdx.x;
  const int wg   = blockIdx.x;
  const int lane = tid & 63;
  const int w    = tid >> 6;            // wave 0..7 (K-split owner)
  const int l15  = lane & 15;
  const int kb   = lane >> 4;           // k-block / C-row group
  const int mcl  = (l15 < 8) ? l15 : 7; // clamped batch row (8 real of M=16)
  const int grp = wg & 7;               // batch group (pure wg-arithmetic)
  const int cg  = wg >> 3;              // col group 0..31 (coverage by arithmetic)
  const int colbase = cg * 32;
  uint32_t* myflag = p.flags + (grp * 32 + cg) * 16;

  // zero own flag (agent — only class ever used on flags); replay-safe behind barrier
  if (tid == 0)
    __hip_atomic_store(myflag, 0u, __ATOMIC_RELAXED, __HIP_MEMORY_SCOPE_AGENT);

  // ---- weights: 48 K-chunks of 32; wave w owns chunks {w+8i, i=0..5}.
  //      i=0,1 x-chunks; i=2..5 h-chunks. i<5 -> VGPR, i==5 -> LDS.
  bf16x8 wreg[5][8];
  #pragma unroll
  for (int i = 0; i < 6; ++i) {
    const int kg = (w + 8 * i) * 32 + kb * 8;
    #pragma unroll
    for (int n = 0; n < 8; ++n) {
      const int r = n * 16 + l15;                       // local gate row 0..127
      const int R = (r >> 5) * H_ + colbase + (r & 31); // global gate row
      const float* s = (kg < I_) ? (p.Wi + (size_t)R * I_ + kg)
                                 : (p.Wh + (size_t)R * H_ + (kg - I_));
      bf16x8 v = cvt8(*(const float4*)s, *(const float4*)(s + 4));
      if (i < 5) wreg[i][n] = v;
      else       *(bf16x8*)&wlds[w][n][lane][0] = v;
    }
  }

  // ---- finisher state: tid<256 owns (b = tid&7, col = colbase + tid>>3) ----
  const int fb  = tid & 7;
  const int fcc = tid >> 3;             // 0..31 for tid<256
  const int col = colbase + (fcc & 31);
  const int gb  = grp * 8 + fb;
  float bias_i = 0, bias_f = 0, bias_g = 0, bias_o = 0, c = 0, hy_prev = 0;
  if (tid < 256) {
    float tg = p.bt[col];
    for (int j = 0; j < TOP_ / 4; ++j) {
      float4 tv = ((const float4*)(p.topic + (size_t)gb * TOP_))[j];
      float4 wv = ((const float4*)(p.Wt + (size_t)col * TOP_))[j];
      tg += tv.x * wv.x + tv.y * wv.y + tv.z * wv.z + tv.w * wv.w;
    }
    bias_i = p.bi[col]        + p.bh[col]        + tg;
    bias_f = p.bi[H_ + col]   + p.bh[H_ + col]   + tg;
    bias_g = p.bi[2*H_ + col] + p.bh[2*H_ + col];
    bias_o = p.bi[3*H_ + col] + p.bh[3*H_ + col];
    c = p.c0[(size_t)gb * H_ + col];
    hlds[fb][fcc] = (ushort)__builtin_bit_cast(
        uint16_t, (__bf16)p.h0[(size_t)gb * H_ + col]);
  }
  __syncthreads();

  // ---- publish h(0) -> slot 0 (sc01, full coverage: 32 lanes x 16B) ----
  if (w == 0 && lane < 32) {
    const int b = lane >> 2, off = (lane & 3) * 8;
    u32x4 v = *(const u32x4*)&hlds[b][off];
    st16_sc01(p.hs + ((size_t)(0 * 8 + grp) * 8 + b) * 1024 + colbase + off, v);
  }
  WAITV0();
  __syncthreads();   // all publishes + flag-zeros of this WG complete (vmcnt drained)

  // ---- one-time IF$ barrier, then open flags ----
  if (tid == 0) {
    __hip_atomic_fetch_add(p.bar, 1u, __ATOMIC_RELAXED, __HIP_MEMORY_SCOPE_AGENT);
    uint32_t it = 0, v;
    do { v = ld32_sc01(p.bar); WAITV0(); } while (v < NWG && ++it < (1u << 24));
    __hip_atomic_store(myflag, 1u, __ATOMIC_RELAXED, __HIP_MEMORY_SCOPE_AGENT);
  }
  __syncthreads();

  for (int t = 0; t < T_; ++t) {
    const uint32_t want = (uint32_t)(t + 1);

    // issue x(t) loads (plain; latency hides under the gate poll).
    float4 xa[2][2];
    #pragma unroll
    for (int i = 0; i < 2; ++i) {
      const float* s = p.x + ((size_t)(grp * 8 + mcl) * T_ + t) * I_ + (w + 8 * i) * 32 + kb * 8;
      xa[i][0] = *(const float4*)s;
      xa[i][1] = *(const float4*)(s + 4);
    }

    // wave-granular gate: wave w consumes h cols from producers cg = w + 8*{0,1,2,3}.
    // s_sleep(1) backoff is REQUIRED: every no-sleep variant (R13/R14/R15) read stale h —
    // flag becomes IF$-visible before the data stores; sleep-quantized discovery
    // plus the settle below keeps consumption past the visibility-skew window.
    {
      const uint32_t* fl = p.flags + (grp * 32 + (w + 8 * (lane & 3))) * 16;
      uint32_t it = 0;
      for (;;) {
        uint32_t v = ld32_sc01(fl);
        WAITV0();
        if (!__any((int)(v < want)) || ++it > (1u << 20)) break;  // bounded: fail-fast
        __builtin_amdgcn_s_sleep(1);
      }
      __builtin_amdgcn_s_sleep(2);   // settle: cover flag-vs-data visibility skew (~128 cy)
      __builtin_amdgcn_sched_barrier(0);
    }

    // h(t) loads (IF$): 4 chunks x 16B per lane — issued immediately after gate
    const uint16_t* hcur = p.hs + (size_t)(((t & 1) * 8 + grp) * 8) * 1024;
    u32x4 hz[4];
    #pragma unroll
    for (int i = 2; i < 6; ++i) {
      const void* a = hcur + (size_t)mcl * 1024 + ((w + 8 * i) * 32 - I_) + kb * 8;
      hz[i - 2] = ld16_sc01(a);
    }

    // deferred out(t-1): issued AFTER the gate so its HBM ack overlaps the
    // h-load RT inside the pre-MFMA vmcnt(0) (in-order retire: wait = max, not sum)
    if (t > 0 && tid < 256)
      __builtin_nontemporal_store(hy_prev, &p.out[((size_t)gb * T_ + (t - 1)) * H_ + col]);

    // x MFMAs (registers; overlap h-load + out-store latency)
    f32x4 acc[8];
    #pragma unroll
    for (int n = 0; n < 8; ++n) acc[n] = (f32x4){0, 0, 0, 0};
    #pragma unroll
    for (int i = 0; i < 2; ++i) {
      bf16x8 af = cvt8(xa[i][0], xa[i][1]);
      #pragma unroll
      for (int n = 0; n < 8; ++n)
        acc[n] = __builtin_amdgcn_mfma_f32_16x16x32_bf16(af, wreg[i][n], acc[n], 0, 0, 0);
    }

    WAITV0();
    __builtin_amdgcn_sched_barrier(0);

    // h MFMAs
    #pragma unroll
    for (int i = 2; i < 6; ++i) {
      union { u32x4 q; bf16x8 b; } z; z.q = hz[i - 2];
      #pragma unroll
      for (int n = 0; n < 8; ++n) {
        bf16x8 bb = (i < 5) ? wreg[i][n] : *(const bf16x8*)&wlds[w][n][lane][0];
        acc[n] = __builtin_amdgcn_mfma_f32_16x16x32_bf16(z.b, bb, acc[n], 0, 0, 0);
      }
    }

    // per-wave K-partials -> LDS (real batch rows only)
    #pragma unroll
    for (int n = 0; n < 8; ++n)
      if (kb < 2)
        *(f32x4*)&pl[w][n * 16 + l15][kb * 4] = acc[n];
    __syncthreads();   // sync1

    // reduce 8 K-partials, finish gates
    float hy = 0.f;
    if (tid < 256) {
      float g0 = 0, g1 = 0, g2 = 0, g3 = 0;
      #pragma unroll
      for (int ww = 0; ww < 8; ++ww) {
        g0 += pl[ww][ 0 + fcc][fb];
        g1 += pl[ww][32 + fcc][fb];
        g2 += pl[ww][64 + fcc][fb];
        g3 += pl[ww][96 + fcc][fb];
      }
      float ig  = sigm(g0 + bias_i);
      float fg  = sigm(g1 + bias_f);
      float cg_ = tanh_fast(g2 + bias_g);
      float og  = sigm(g3 + bias_o);
      c = fg * c + ig * cg_;
      hy = og * tanh_fast(c);
      if (t < T_ - 1) {
        hlds[fb][fcc] = (ushort)__builtin_bit_cast(uint16_t, (__bf16)hy);
      } else {
        __builtin_nontemporal_store(hy, &p.out[((size_t)gb * T_ + t) * H_ + col]);
        p.hN[(size_t)gb * H_ + col] = hy;
        p.cN[(size_t)gb * H_ + col] = c;
      }
      hy_prev = hy;
    }
    __syncthreads();   // sync2: hlds ready; pl reads done

    // publish h(t+1) -> slot (t+1)&1 (sc01) + flag (agent); others run ahead
    if (t < T_ - 1) {
      if (w == 0) {
        if (lane < 32) {
          const int b = lane >> 2, off = (lane & 3) * 8;
          u32x4 v = *(const u32x4*)&hlds[b][off];
          st16_sc01(p.hs + ((size_t)((((t + 1) & 1) * 8 + grp) * 8 + b) * 1024
                            + colbase + off), v);
        }
        WAITV0();                      // publishes committed at IF$ before flag
        if (tid == 0)
          __hip_atomic_store(myflag, want + 1u,
                             __ATOMIC_RELAXED, __HIP_MEMORY_SCOPE_AGENT);
      }
    }
  }
}

extern "C" void kernel_launch(void* const* d_in, const int* in_sizes, int n_in,
                              void* d_out, int out_size, void* d_ws, size_t ws_size,
                              hipStream_t stream) {
  (void)in_sizes; (void)n_in; (void)out_size; (void)ws_size;

  P p;
  p.x     = (const float*)d_in[0];
  p.h0    = (const float*)d_in[1];
  p.c0    = (const float*)d_in[2];
  p.topic = (const float*)d_in[3];
  p.Wi    = (const float*)d_in[4];
  p.bi    = (const float*)d_in[5];
  p.Wh    = (const float*)d_in[6];
  p.bh    = (const float*)d_in[7];
  p.Wt    = (const float*)d_in[8];
  p.bt    = (const float*)d_in[9];

  float* out = (float*)d_out;
  p.out = out;
  p.hN  = out + (size_t)B_ * T_ * H_;
  p.cN  = p.hN + (size_t)B_ * H_;

  uint8_t* ws = (uint8_t*)d_ws;
  p.hs    = (uint16_t*)(ws);                    // 2*8*8*1024*2 = 262144 B
  p.flags = (uint32_t*)(ws + 262144);           // 16384 B
  p.bar   = (uint32_t*)(ws + 262144 + 16384);   // 64 B

  lstm_init<<<dim3(1), dim3(64), 0, stream>>>(p);
  lstm_persist<<<dim3(NWG), dim3(NTHR), 0, stream>>>(p);
}

// Round 17
// 3957.585 us; speedup vs baseline: 1.0501x; 1.0501x over previous
//
#include <hip/hip_runtime.h>
#include <hip/hip_bf16.h>
#include <stdint.h>

#define B_   64
#define T_   1024
#define I_   512
#define H_   1024
#define TOP_ 256
#define NWG  256
#define NTHR 512
#define HBS  1032   // hbuf row stride (ushorts): 2064B rows -> 4-bank skew, <=4-way reads

typedef __bf16 bf16x8 __attribute__((ext_vector_type(8)));
typedef float  f32x4  __attribute__((ext_vector_type(4)));
typedef uint32_t u32x4 __attribute__((ext_vector_type(4)));

struct P {
  const float *x, *h0, *c0, *topic, *Wi, *bi, *Wh, *bh, *Wt, *bt;
  float *out, *hN, *cN;
  uint16_t *hs;       // h slots [2][8 grp][8 b][1024] bf16 — sc01/IF$ ops ONLY
  uint32_t *flags;    // [8 grp][32 cg], 64B apart — agent st / sc01 ld ONLY
  uint32_t *bar;      // prologue barrier counter
};

__device__ __forceinline__ bf16x8 cvt8(float4 f0, float4 f1) {
  bf16x8 v;
  v[0]=(__bf16)f0.x; v[1]=(__bf16)f0.y; v[2]=(__bf16)f0.z; v[3]=(__bf16)f0.w;
  v[4]=(__bf16)f1.x; v[5]=(__bf16)f1.y; v[6]=(__bf16)f1.z; v[7]=(__bf16)f1.w;
  return v;
}
__device__ __forceinline__ float sigm(float x) { return 1.f / (1.f + __expf(-x)); }
__device__ __forceinline__ float tanh_fast(float z) {
  z = fminf(fmaxf(z, -15.f), 15.f);
  float e = __expf(2.f * z);
  return (e - 1.f) / (e + 1.f);
}
// IF$ coherence point (cross-XCD coherent) — the ONLY class on hs/flags/bar
__device__ __forceinline__ u32x4 ld16_sc01(const void* a) {
  u32x4 r; asm volatile("global_load_dwordx4 %0, %1, off sc0 sc1" : "=v"(r) : "v"(a) : "memory"); return r;
}
__device__ __forceinline__ uint32_t ld32_sc01(const void* a) {
  uint32_t r; asm volatile("global_load_dword %0, %1, off sc0 sc1" : "=v"(r) : "v"(a) : "memory"); return r;
}
__device__ __forceinline__ void st16_sc01(void* a, u32x4 v) {
  asm volatile("global_store_dwordx4 %0, %1, off sc0 sc1" :: "v"(a), "v"(v) : "memory");
}
#define WAITV0() asm volatile("s_waitcnt vmcnt(0)" ::: "memory")

__global__ void lstm_init(P p) {
  if (threadIdx.x == 0)
    __hip_atomic_store(p.bar, 0u, __ATOMIC_RELAXED, __HIP_MEMORY_SCOPE_AGENT);
}

__global__ __launch_bounds__(NTHR, 2) void lstm_persist(P p) {
  __shared__ ushort wlds[8][8][64][8];              // 64 KB: weight chunk i==5
  __shared__ float  pl[8][132][8];                  // 33.8 KB
  __shared__ __align__(16) ushort hlds[8][32];      // 512 B: publish gather
  __shared__ __align__(16) ushort hbuf[8][HBS];     // 16.5 KB: staged h(t)

  const int tid  = threadIdx.x;
  const int wg   = blockIdx.x;
  const int lane = tid & 63;
  const int w    = tid >> 6;            // wave 0..7 (K-split owner)
  const int l15  = lane & 15;
  const int kb   = lane >> 4;
  const int mcl  = (l15 < 8) ? l15 : 7;
  const int grp = wg & 7;
  const int cg  = wg >> 3;
  const int colbase = cg * 32;
  uint32_t* myflag = p.flags + (grp * 32 + cg) * 16;

  // staging identity: wave w stages cols [w*128,(w+1)*128) x 8 rows;
  // thread (w,lane): row = lane>>3, 16-ushort sub = lane&7 -> 32B, ONE producer.
  const int srow = lane >> 3;
  const int sk0  = w * 128 + (lane & 7) * 16;
  const uint32_t* sfl = p.flags + (grp * 32 + (sk0 >> 5)) * 16;

  if (tid == 0)
    __hip_atomic_store(myflag, 0u, __ATOMIC_RELAXED, __HIP_MEMORY_SCOPE_AGENT);

  // ---- weights: wave w owns chunks {w+8i, i=0..5}; i<5 VGPR, i==5 LDS ----
  bf16x8 wreg[5][8];
  #pragma unroll
  for (int i = 0; i < 6; ++i) {
    const int kg = (w + 8 * i) * 32 + kb * 8;
    #pragma unroll
    for (int n = 0; n < 8; ++n) {
      const int r = n * 16 + l15;
      const int R = (r >> 5) * H_ + colbase + (r & 31);
      const float* s = (kg < I_) ? (p.Wi + (size_t)R * I_ + kg)
                                 : (p.Wh + (size_t)R * H_ + (kg - I_));
      bf16x8 v = cvt8(*(const float4*)s, *(const float4*)(s + 4));
      if (i < 5) wreg[i][n] = v;
      else       *(bf16x8*)&wlds[w][n][lane][0] = v;
    }
  }

  // ---- finisher state ----
  const int fb  = tid & 7;
  const int fcc = tid >> 3;
  const int col = colbase + (fcc & 31);
  const int gb  = grp * 8 + fb;
  float bias_i = 0, bias_f = 0, bias_g = 0, bias_o = 0, c = 0, hy_prev = 0;
  if (tid < 256) {
    float tg = p.bt[col];
    for (int j = 0; j < TOP_ / 4; ++j) {
      float4 tv = ((const float4*)(p.topic + (size_t)gb * TOP_))[j];
      float4 wv = ((const float4*)(p.Wt + (size_t)col * TOP_))[j];
      tg += tv.x * wv.x + tv.y * wv.y + tv.z * wv.z + tv.w * wv.w;
    }
    bias_i = p.bi[col]        + p.bh[col]        + tg;
    bias_f = p.bi[H_ + col]   + p.bh[H_ + col]   + tg;
    bias_g = p.bi[2*H_ + col] + p.bh[2*H_ + col];
    bias_o = p.bi[3*H_ + col] + p.bh[3*H_ + col];
    c = p.c0[(size_t)gb * H_ + col];
    hlds[fb][fcc] = (ushort)__builtin_bit_cast(
        uint16_t, (__bf16)p.h0[(size_t)gb * H_ + col]);
  }
  __syncthreads();

  // ---- publish h(0) -> slot 0 (sc01, full coverage) ----
  if (w == 0 && lane < 32) {
    const int b = lane >> 2, off = (lane & 3) * 8;
    u32x4 v = *(const u32x4*)&hlds[b][off];
    st16_sc01(p.hs + ((size_t)(0 * 8 + grp) * 8 + b) * 1024 + colbase + off, v);
  }
  WAITV0();
  __syncthreads();

  // ---- one-time IF$ barrier, then open flags ----
  if (tid == 0) {
    __hip_atomic_fetch_add(p.bar, 1u, __ATOMIC_RELAXED, __HIP_MEMORY_SCOPE_AGENT);
    uint32_t it = 0, v;
    do { v = ld32_sc01(p.bar); WAITV0(); } while (v < NWG && ++it < (1u << 24));
    __hip_atomic_store(myflag, 1u, __ATOMIC_RELAXED, __HIP_MEMORY_SCOPE_AGENT);
  }
  __syncthreads();

  for (int t = 0; t < T_; ++t) {
    const uint32_t want = (uint32_t)(t + 1);

    // deferred out(t-1) BEFORE the gate (R12 schedule — measured fastest):
    // its HBM ack drains during the first poll's vmcnt(0).
    if (t > 0 && tid < 256)
      __builtin_nontemporal_store(hy_prev, &p.out[((size_t)gb * T_ + (t - 1)) * H_ + col]);

    // x(t) loads (plain; latency hides under the gate poll)
    float4 xa[2][2];
    #pragma unroll
    for (int i = 0; i < 2; ++i) {
      const float* s = p.x + ((size_t)(grp * 8 + mcl) * T_ + t) * I_ + (w + 8 * i) * 32 + kb * 8;
      xa[i][0] = *(const float4*)s;
      xa[i][1] = *(const float4*)(s + 4);
    }

    // per-thread gate on the ONE producer covering this thread's staged 32B.
    // s_sleep(1) backoff REQUIRED (R13/14/15 all failed without it: flag becomes
    // IF$-visible before data); s_sleep(2) settle covers the residual skew (R16-proven).
    {
      uint32_t v, it = 0;
      for (;;) {
        v = ld32_sc01(sfl);
        WAITV0();
        if (v >= want || ++it > (1u << 20)) break;
        __builtin_amdgcn_s_sleep(1);
      }
      __builtin_amdgcn_s_sleep(2);
      __builtin_amdgcn_sched_barrier(0);
    }

    // coalesced stage: 32B/thread, 256B runs per wave (sc01 — proven class).
    const uint16_t* hsl = p.hs + (size_t)(((t & 1) * 8 + grp) * 8 + srow) * 1024 + sk0;
    u32x4 sv0 = ld16_sc01(hsl);
    u32x4 sv1 = ld16_sc01(hsl + 8);

    // x MFMAs overlap stage RT (xa loads are OLDER -> counted vmcnt lets these run)
    f32x4 acc[8];
    #pragma unroll
    for (int n = 0; n < 8; ++n) acc[n] = (f32x4){0, 0, 0, 0};
    #pragma unroll
    for (int i = 0; i < 2; ++i) {
      bf16x8 af = cvt8(xa[i][0], xa[i][1]);
      #pragma unroll
      for (int n = 0; n < 8; ++n)
        acc[n] = __builtin_amdgcn_mfma_f32_16x16x32_bf16(af, wreg[i][n], acc[n], 0, 0, 0);
    }

    WAITV0();
    __builtin_amdgcn_sched_barrier(0);
    *(u32x4*)&hbuf[srow][sk0]     = sv0;
    *(u32x4*)&hbuf[srow][sk0 + 8] = sv1;
    __syncthreads();   // sync0: h(t) fully staged by all waves

    // h MFMAs: A-frags from LDS (b128; 2064B row skew -> <=4-way banks, dup lanes)
    #pragma unroll
    for (int i = 2; i < 6; ++i) {
      const int koff = 32 * w + 256 * (i - 2) + 8 * kb;
      union { u32x4 q; bf16x8 b; } z;
      z.q = *(const u32x4*)&hbuf[mcl][koff];
      #pragma unroll
      for (int n = 0; n < 8; ++n) {
        bf16x8 bb = (i < 5) ? wreg[i][n] : *(const bf16x8*)&wlds[w][n][lane][0];
        acc[n] = __builtin_amdgcn_mfma_f32_16x16x32_bf16(z.b, bb, acc[n], 0, 0, 0);
      }
    }

    // per-wave K-partials -> LDS
    #pragma unroll
    for (int n = 0; n < 8; ++n)
      if (kb < 2)
        *(f32x4*)&pl[w][n * 16 + l15][kb * 4] = acc[n];
    __syncthreads();   // sync1

    // reduce 8 K-partials, finish gates
    float hy = 0.f;
    if (tid < 256) {
      float g0 = 0, g1 = 0, g2 = 0, g3 = 0;
      #pragma unroll
      for (int ww = 0; ww < 8; ++ww) {
        g0 += pl[ww][ 0 + fcc][fb];
        g1 += pl[ww][32 + fcc][fb];
        g2 += pl[ww][64 + fcc][fb];
        g3 += pl[ww][96 + fcc][fb];
      }
      float ig  = sigm(g0 + bias_i);
      float fg  = sigm(g1 + bias_f);
      float cg_ = tanh_fast(g2 + bias_g);
      float og  = sigm(g3 + bias_o);
      c = fg * c + ig * cg_;
      hy = og * tanh_fast(c);
      if (t < T_ - 1) {
        hlds[fb][fcc] = (ushort)__builtin_bit_cast(uint16_t, (__bf16)hy);
      } else {
        __builtin_nontemporal_store(hy, &p.out[((size_t)gb * T_ + t) * H_ + col]);
        p.hN[(size_t)gb * H_ + col] = hy;
        p.cN[(size_t)gb * H_ + col] = c;
      }
      hy_prev = hy;
    }
    __syncthreads();   // sync2: hlds ready; pl reads done

    // publish h(t+1) (sc01) + flag (agent) — wave0; others run ahead
    if (t < T_ - 1) {
      if (w == 0) {
        if (lane < 32) {
          const int b = lane >> 2, off = (lane & 3) * 8;
          u32x4 v = *(const u32x4*)&hlds[b][off];
          st16_sc01(p.hs + ((size_t)((((t + 1) & 1) * 8 + grp) * 8 + b) * 1024
                            + colbase + off), v);
        }
        WAITV0();                      // publishes committed at IF$ before flag
        if (tid == 0)
          __hip_atomic_store(myflag, want + 1u,
                             __ATOMIC_RELAXED, __HIP_MEMORY_SCOPE_AGENT);
      }
    }
  }
}

extern "C" void kernel_launch(void* const* d_in, const int* in_sizes, int n_in,
                              void* d_out, int out_size, void* d_ws, size_t ws_size,
                              hipStream_t stream) {
  (void)in_sizes; (void)n_in; (void)out_size; (void)ws_size;

  P p;
  p.x     = (const float*)d_in[0];
  p.h0    = (const float*)d_in[1];
  p.c0    = (const float*)d_in[2];
  p.topic = (const float*)d_in[3];
  p.Wi    = (const float*)d_in[4];
  p.bi    = (const float*)d_in[5];
  p.Wh    = (const float*)d_in[6];
  p.bh    = (const float*)d_in[7];
  p.Wt    = (const float*)d_in[8];
  p.bt    = (const float*)d_in[9];

  float* out = (float*)d_out;
  p.out = out;
  p.hN  = out + (size_t)B_ * T_ * H_;
  p.cN  = p.hN + (size_t)B_ * H_;

  uint8_t* ws = (uint8_t*)d_ws;
  p.hs    = (uint16_t*)(ws);                    // 262144 B
  p.flags = (uint32_t*)(ws + 262144);           // 16384 B
  p.bar   = (uint32_t*)(ws + 262144 + 16384);   // 64 B

  lstm_init<<<dim3(1), dim3(64), 0, stream>>>(p);
  lstm_persist<<<dim3(NWG), dim3(NTHR), 0, stream>>>(p);
}